// Round 1
// baseline (633.239 us; speedup 1.0000x reference)
//
#include <hip/hip_runtime.h>
#include <stdint.h>
#include <stddef.h>

typedef __bf16 bf16_t;
typedef __bf16 bf16x4 __attribute__((ext_vector_type(4)));
typedef __bf16 bf16x8 __attribute__((ext_vector_type(8)));
typedef float  f32x4  __attribute__((ext_vector_type(4)));

#define H_   12
#define N_   49
#define C_   384
#define D_   32
#define NW_  64
#define C3_  1152

// LDS layout (bytes)
#define XS_STRIDE   392        // bf16 elems per row of x / attn_out tiles (384 + 8 pad)
#define QKV_OFF     38416      // byte offset of qkv region
#define QKV_STRIDE  1160       // bf16 elems per row (1152 + 8 pad)
#define SMEM_BYTES  152096     // 38416 + 49*1160*2
#define PBUF_BYTES  6272       // 49 rows * 64 cols * 2B per-wave P buffer

#define WQKV_ELEMS  (C3_ * C_)   // 442368
#define WPROJ_ELEMS (C_ * C_)    // 147456

// ---------------------------------------------------------------------------
// Prep: cast + transpose + frag-order the weights into workspace.
// Frag order: elem((nj*12 + ks)*64 + lane)*8 + j  holds  W[k][n] with
//   n = nj*16 + (lane&15), k = ks*32 + (lane>>4)*8 + j
// so a wave's B-fragment load is lane-contiguous (1 KB per fragment).
// ---------------------------------------------------------------------------
__global__ void prep_weights(const float* __restrict__ qkv_w,
                             const float* __restrict__ proj_w,
                             bf16_t* __restrict__ wqkvT,
                             bf16_t* __restrict__ wprojT)
{
    int idx = blockIdx.x * 256 + threadIdx.x;
    if (idx < WQKV_ELEMS) {
        int j    = idx & 7;
        int lane = (idx >> 3) & 63;
        int rest = idx >> 9;
        int ks   = rest % 12;
        int nj   = rest / 12;
        int n = nj * 16 + (lane & 15);
        int k = ks * 32 + (lane >> 4) * 8 + j;
        wqkvT[idx] = (bf16_t)qkv_w[k * C3_ + n];
    } else {
        int i2 = idx - WQKV_ELEMS;
        if (i2 < WPROJ_ELEMS) {
            int j    = i2 & 7;
            int lane = (i2 >> 3) & 63;
            int rest = i2 >> 9;
            int ks   = rest % 12;
            int nj   = rest / 12;
            int n = nj * 16 + (lane & 15);
            int k = ks * 32 + (lane >> 4) * 8 + j;
            wprojT[i2] = (bf16_t)proj_w[k * C_ + n];
        }
    }
}

// ---------------------------------------------------------------------------
// Fused per-window kernel: one block per window b.
// ---------------------------------------------------------------------------
__global__ __launch_bounds__(512, 2)
void fused_window_attn(const float* __restrict__ x,
                       const float* __restrict__ mask,
                       const float* __restrict__ qkv_b,
                       const float* __restrict__ proj_b,
                       const float* __restrict__ rpb_all,
                       const bf16_t* __restrict__ wqkvT,
                       const bf16_t* __restrict__ wprojT,
                       float* __restrict__ out)
{
    __shared__ __align__(16) unsigned char smem[SMEM_BYTES];
    bf16_t* xs  = (bf16_t*)smem;               // phase 1/2: 49 x 392 bf16
    bf16_t* qkv = (bf16_t*)(smem + QKV_OFF);   // phase 2/3: 49 x 1160 bf16
    bf16_t* ao  = (bf16_t*)smem;               // phase 4: attn_out 49 x 392 (reuses xs/P)

    const int tid  = threadIdx.x;
    const int wave = tid >> 6;
    const int lane = tid & 63;
    const int q4   = lane >> 4;
    const int l15  = lane & 15;
    const int b    = blockIdx.x;

    const f32x4 z4 = {0.f, 0.f, 0.f, 0.f};

    // ---------------- phase 1: x[b] -> bf16 LDS ----------------
    {
        const float* xg = x + (size_t)b * (N_ * C_);
        for (int t = tid; t < (N_ * C_) / 4; t += 512) {
            float4 v = ((const float4*)xg)[t];
            int r = (t * 4) / C_;
            int c = (t * 4) % C_;
            bf16x4 o;
            o[0] = (bf16_t)v.x; o[1] = (bf16_t)v.y;
            o[2] = (bf16_t)v.z; o[3] = (bf16_t)v.w;
            *(bf16x4*)(xs + r * XS_STRIDE + c) = o;
        }
    }
    __syncthreads();

    // ---------------- phase 2: qkv = xs @ Wqkv + b -> LDS (bf16) ----------------
    {
        f32x4 acc[9][4];
        #pragma unroll
        for (int jj = 0; jj < 9; ++jj)
            #pragma unroll
            for (int mi = 0; mi < 4; ++mi)
                acc[jj][mi] = z4;

        const int nj0 = wave * 9;   // 8 waves * 9 = 72 N-tiles of 16 = 1152
        for (int ks = 0; ks < 12; ++ks) {
            bf16x8 a[4];
            #pragma unroll
            for (int mi = 0; mi < 4; ++mi) {
                int m = mi * 16 + l15; if (m > 48) m = 48;  // M padding: dup row 48
                a[mi] = *(const bf16x8*)(xs + m * XS_STRIDE + ks * 32 + q4 * 8);
            }
            #pragma unroll
            for (int jj = 0; jj < 9; ++jj) {
                bf16x8 bfr = *(const bf16x8*)(wqkvT +
                    (size_t)(((nj0 + jj) * 12 + ks) * 64 + lane) * 8);
                #pragma unroll
                for (int mi = 0; mi < 4; ++mi)
                    acc[jj][mi] = __builtin_amdgcn_mfma_f32_16x16x32_bf16(
                        a[mi], bfr, acc[jj][mi], 0, 0, 0);
            }
        }
        #pragma unroll
        for (int jj = 0; jj < 9; ++jj) {
            const int n = (nj0 + jj) * 16 + l15;
            const float bias = qkv_b[n];
            #pragma unroll
            for (int mi = 0; mi < 4; ++mi) {
                #pragma unroll
                for (int r = 0; r < 4; ++r) {
                    const int m = mi * 16 + q4 * 4 + r;   // C/D: row=(lane>>4)*4+reg
                    if (m < N_)
                        qkv[m * QKV_STRIDE + n] = (bf16_t)(acc[jj][mi][r] + bias);
                }
            }
        }
    }
    __syncthreads();

    // ---------------- phase 3: per-head attention (waves 0..5, 2 heads each) ----
    bf16x4 okeep[2][4][2];   // [head][mi][dd-tile] bf16 rows r=0..3
    if (wave < 6) {
        bf16_t* pb = (bf16_t*)(smem + wave * PBUF_BYTES);  // P buffer (xs is dead)
        #pragma unroll 1
        for (int hh = 0; hh < 2; ++hh) {
            const int h = wave * 2 + hh;

            // S = Q K^T  (d=32 == one K step)
            bf16x8 qf[4], kf[4];
            #pragma unroll
            for (int mi = 0; mi < 4; ++mi) {
                int m = mi * 16 + l15; if (m > 48) m = 48;
                qf[mi] = *(const bf16x8*)(qkv + m * QKV_STRIDE + h * D_ + q4 * 8);
            }
            #pragma unroll
            for (int ni = 0; ni < 4; ++ni) {
                int n = ni * 16 + l15; if (n > 48) n = 48;
                kf[ni] = *(const bf16x8*)(qkv + n * QKV_STRIDE + C_ + h * D_ + q4 * 8);
            }
            f32x4 sacc[4][4];
            #pragma unroll
            for (int mi = 0; mi < 4; ++mi)
                #pragma unroll
                for (int ni = 0; ni < 4; ++ni)
                    sacc[mi][ni] = __builtin_amdgcn_mfma_f32_16x16x32_bf16(
                        qf[mi], kf[ni], z4, 0, 0, 0);

            // scale + rel_pos_bias + mask, exp (max-free: |S| ~ O(1) here), row sums
            const float* rpb = rpb_all + h * (N_ * N_);
            const float* msk = mask + (size_t)(b & (NW_ - 1)) * (N_ * N_);
            f32x4 rsum[4];
            #pragma unroll
            for (int mi = 0; mi < 4; ++mi) {
                rsum[mi] = z4;
                #pragma unroll
                for (int ni = 0; ni < 4; ++ni) {
                    const int n = ni * 16 + l15;
                    #pragma unroll
                    for (int r = 0; r < 4; ++r) {
                        const int m = mi * 16 + q4 * 4 + r;
                        float s = 0.f;
                        if (m < N_ && n < N_)
                            s = __expf(sacc[mi][ni][r] * 0.17677669529663687f
                                       + rpb[m * N_ + n] + msk[m * N_ + n]);
                        sacc[mi][ni][r] = s;
                        rsum[mi][r] += s;
                    }
                }
                #pragma unroll
                for (int d = 1; d < 16; d <<= 1) {
                    #pragma unroll
                    for (int r = 0; r < 4; ++r)
                        rsum[mi][r] += __shfl_xor(rsum[mi][r], d);
                }
            }

            // write P (bf16) to swizzled LDS buffer: cols 49..63 are exact zeros
            #pragma unroll
            for (int mi = 0; mi < 4; ++mi) {
                f32x4 rinv;
                #pragma unroll
                for (int r = 0; r < 4; ++r) rinv[r] = __builtin_amdgcn_rcpf(rsum[mi][r]);
                #pragma unroll
                for (int ni = 0; ni < 4; ++ni) {
                    const int n = ni * 16 + l15;
                    #pragma unroll
                    for (int r = 0; r < 4; ++r) {
                        const int m = mi * 16 + q4 * 4 + r;
                        if (m < N_) {
                            const int blk = (n >> 3) ^ (m & 7);   // XOR swizzle
                            pb[m * 64 + blk * 8 + (n & 7)] = (bf16_t)(sacc[mi][ni][r] * rinv[r]);
                        }
                    }
                }
            }

            // out_h = P @ V   (K = 49 padded to 64; P cols >=49 are zero)
            f32x4 oacc[4][2];
            #pragma unroll
            for (int mi = 0; mi < 4; ++mi)
                #pragma unroll
                for (int t = 0; t < 2; ++t) oacc[mi][t] = z4;

            #pragma unroll
            for (int ks2 = 0; ks2 < 2; ++ks2) {
                bf16x8 pf[4];
                #pragma unroll
                for (int mi = 0; mi < 4; ++mi) {
                    const int m = mi * 16 + l15;       // rows 49..63: stale-finite, discarded
                    const int blk = (ks2 * 4 + q4) ^ (m & 7);
                    pf[mi] = *(const bf16x8*)(pb + m * 64 + blk * 8);
                }
                bf16x8 vf[2];
                #pragma unroll
                for (int t = 0; t < 2; ++t) {
                    #pragma unroll
                    for (int i = 0; i < 8; ++i) {
                        int n = ks2 * 32 + q4 * 8 + i; if (n > 48) n = 48; // P=0 there
                        vf[t][i] = qkv[n * QKV_STRIDE + 2 * C_ + h * D_ + t * 16 + l15];
                    }
                }
                #pragma unroll
                for (int mi = 0; mi < 4; ++mi)
                    #pragma unroll
                    for (int t = 0; t < 2; ++t)
                        oacc[mi][t] = __builtin_amdgcn_mfma_f32_16x16x32_bf16(
                            pf[mi], vf[t], oacc[mi][t], 0, 0, 0);
            }
            #pragma unroll
            for (int mi = 0; mi < 4; ++mi)
                #pragma unroll
                for (int t = 0; t < 2; ++t) {
                    bf16x4 o;
                    #pragma unroll
                    for (int r = 0; r < 4; ++r) o[r] = (bf16_t)oacc[mi][t][r];
                    okeep[hh][mi][t] = o;
                }
        }
    }
    __syncthreads();   // everyone done reading qkv / P regions

    // stage attn_out (head-concat layout) into LDS for the proj GEMM
    if (wave < 6) {
        #pragma unroll
        for (int hh = 0; hh < 2; ++hh) {
            const int h = wave * 2 + hh;
            #pragma unroll
            for (int mi = 0; mi < 4; ++mi)
                #pragma unroll
                for (int t = 0; t < 2; ++t)
                    #pragma unroll
                    for (int r = 0; r < 4; ++r) {
                        const int m = mi * 16 + q4 * 4 + r;
                        if (m < N_)
                            ao[m * XS_STRIDE + h * D_ + t * 16 + l15] = okeep[hh][mi][t][r];
                    }
        }
    }
    __syncthreads();

    // ---------------- phase 4: out = attn_out @ Wproj + b ----------------
    {
        f32x4 pacc[3][4];
        #pragma unroll
        for (int jj = 0; jj < 3; ++jj)
            #pragma unroll
            for (int mi = 0; mi < 4; ++mi) pacc[jj][mi] = z4;

        const int nj0 = wave * 3;   // 8 waves * 3 = 24 N-tiles of 16 = 384
        for (int ks = 0; ks < 12; ++ks) {
            bf16x8 a[4];
            #pragma unroll
            for (int mi = 0; mi < 4; ++mi) {
                int m = mi * 16 + l15; if (m > 48) m = 48;
                a[mi] = *(const bf16x8*)(ao + m * XS_STRIDE + ks * 32 + q4 * 8);
            }
            #pragma unroll
            for (int jj = 0; jj < 3; ++jj) {
                bf16x8 bfr = *(const bf16x8*)(wprojT +
                    (size_t)(((nj0 + jj) * 12 + ks) * 64 + lane) * 8);
                #pragma unroll
                for (int mi = 0; mi < 4; ++mi)
                    pacc[jj][mi] = __builtin_amdgcn_mfma_f32_16x16x32_bf16(
                        a[mi], bfr, pacc[jj][mi], 0, 0, 0);
            }
        }
        float* og = out + (size_t)b * (N_ * C_);
        #pragma unroll
        for (int jj = 0; jj < 3; ++jj) {
            const int n = (nj0 + jj) * 16 + l15;
            const float bias = proj_b[n];
            #pragma unroll
            for (int mi = 0; mi < 4; ++mi) {
                #pragma unroll
                for (int r = 0; r < 4; ++r) {
                    const int m = mi * 16 + q4 * 4 + r;
                    if (m < N_) og[m * C_ + n] = pacc[jj][mi][r] + bias;
                }
            }
        }
    }
}

// ---------------------------------------------------------------------------
extern "C" void kernel_launch(void* const* d_in, const int* in_sizes, int n_in,
                              void* d_out, int out_size, void* d_ws, size_t ws_size,
                              hipStream_t stream)
{
    const float* x      = (const float*)d_in[0];
    const float* mask   = (const float*)d_in[1];
    const float* qkv_w  = (const float*)d_in[2];
    const float* qkv_b  = (const float*)d_in[3];
    const float* proj_w = (const float*)d_in[4];
    const float* proj_b = (const float*)d_in[5];
    const float* rpb    = (const float*)d_in[6];
    float* out = (float*)d_out;

    bf16_t* wqkvT  = (bf16_t*)d_ws;
    bf16_t* wprojT = wqkvT + WQKV_ELEMS;

    const int prep_total = WQKV_ELEMS + WPROJ_ELEMS;  // 589824
    prep_weights<<<(prep_total + 255) / 256, 256, 0, stream>>>(qkv_w, proj_w, wqkvT, wprojT);
    fused_window_attn<<<2048, 512, 0, stream>>>(x, mask, qkv_b, proj_b, rpb,
                                                wqkvT, wprojT, out);
}

// Round 3
// 545.345 us; speedup vs baseline: 1.1612x; 1.1612x over previous
//
#include <hip/hip_runtime.h>
#include <stdint.h>
#include <stddef.h>

typedef __bf16 bf16_t;
typedef __bf16 bf16x4 __attribute__((ext_vector_type(4)));
typedef __bf16 bf16x8 __attribute__((ext_vector_type(8)));
typedef float  f32x4  __attribute__((ext_vector_type(4)));

#define H_   12
#define N_   49
#define C_   384
#define D_   32
#define NW_  64
#define C3_  1152

// ---- LDS layout (bytes) ----
// region 0: xs (phase1/2: 49 x 392 bf16) / per-wave P buffers (phase 3)
// region 1: q  (phase3: 49 x 392 bf16, [tok][dim]) / ao (phase 4)
// region 2: k  (phase3: 49 x 392 bf16, [tok][dim])
// region 3: vT (phase3: 384 x 56 bf16, [dim][tok]) + 32B read guard
#define XS_STRIDE 392
#define Q_OFF     38416
#define K_OFF     76832
#define VT_OFF    115248
#define VT_STRIDE 56
#define P_STRIDE  72            // elems; per-wave P: 32 rows x 144B = 4608 B
#define SMEM_BYTES 158288       // 115248 + 384*112 + 32 guard

#define WQKV_ELEMS  (C3_ * C_)   // 442368
#define WPROJ_ELEMS (C_ * C_)    // 147456

// ---------------------------------------------------------------------------
// prep_w: coalesced frag-order transpose of both weight matrices.
// out[((ct*12+ks)*64+lane)*8 + j] = W[ks*32+(lane>>4)*8+j][ct*16+(lane&15)]
// ---------------------------------------------------------------------------
__global__ void prep_w(const float* __restrict__ qkv_w,
                       const float* __restrict__ proj_w,
                       bf16_t* __restrict__ wqkvT,
                       bf16_t* __restrict__ wprojT)
{
    __shared__ bf16_t tile[32][72];
    int bid = blockIdx.x;
    const float* src; bf16_t* dst; int NC, ks, g;
    if (bid < 216) { src = qkv_w;  dst = wqkvT;  NC = C3_; ks = bid % 12; g = bid / 12; }
    else { bid -= 216; src = proj_w; dst = wprojT; NC = C_;  ks = bid % 12; g = bid / 12; }
    const int n0 = g * 64;
    const int t = threadIdx.x;
    const int r0 = t >> 6, cc = t & 63;
    #pragma unroll
    for (int p = 0; p < 8; ++p) {
        int row = p * 4 + r0;
        tile[row][cc] = (bf16_t)src[(ks * 32 + row) * NC + n0 + cc];
    }
    __syncthreads();
    const int lane = t & 63, ctl = t >> 6;
    const int q4 = lane >> 4, l15 = lane & 15;
    bf16x8 v;
    #pragma unroll
    for (int j = 0; j < 8; ++j) v[j] = tile[q4 * 8 + j][ctl * 16 + l15];
    *(bf16x8*)(dst + ((size_t)((g * 4 + ctl) * 12 + ks) * 64 + lane) * 8) = v;
}

// ---------------------------------------------------------------------------
// prep_bias: T[w][h][m][n] = (rpb[h][m][n] + mask[w][m][n]) * log2(e), bf16.
// n padded to 64 (zeros). One block per (w,h).
// ---------------------------------------------------------------------------
__global__ void prep_bias(const float* __restrict__ mask,
                          const float* __restrict__ rpb,
                          bf16_t* __restrict__ T)
{
    const int w = blockIdx.x / H_, h = blockIdx.x % H_;
    bf16_t* out = T + (size_t)(w * H_ + h) * (N_ * 64);
    for (int idx = threadIdx.x; idx < N_ * 64; idx += 256) {
        int m = idx >> 6, n = idx & 63;
        float v = 0.f;
        if (n < N_)
            v = (rpb[(h * N_ + m) * N_ + n] + mask[((size_t)w * N_ + m) * N_ + n])
                * 1.4426950408889634f;
        out[idx] = (bf16_t)v;
    }
}

// ---------------------------------------------------------------------------
// Fused per-window kernel: one block per window b, 8 waves.
// ---------------------------------------------------------------------------
__global__ __launch_bounds__(512, 2)
void fused_window_attn(const float* __restrict__ x,
                       const float* __restrict__ qkv_b,
                       const float* __restrict__ proj_b,
                       const bf16_t* __restrict__ wqkvT,
                       const bf16_t* __restrict__ wprojT,
                       const bf16_t* __restrict__ btbl,
                       float* __restrict__ out)
{
    __shared__ __align__(16) unsigned char smem[SMEM_BYTES];
    bf16_t* xs = (bf16_t*)smem;                 // phase 1/2
    bf16_t* qa = (bf16_t*)(smem + Q_OFF);       // q [tok][dim], later ao
    bf16_t* ka = (bf16_t*)(smem + K_OFF);       // k [tok][dim]
    bf16_t* vt = (bf16_t*)(smem + VT_OFF);      // v^T [dim][tok]

    const int tid  = threadIdx.x;
    const int wave = tid >> 6;
    const int lane = tid & 63;
    const int q4   = lane >> 4;
    const int l15  = lane & 15;
    const int b    = blockIdx.x;

    const f32x4 z4 = {0.f, 0.f, 0.f, 0.f};

    // ---------------- phase 1: x[b] -> bf16 LDS; zero vt padding ----------
    {
        // Zero vt token-columns 48..55 of every row + the 32B tail guard.
        // Tokens 49..55 are never written by phase 2 but ARE read (x P==0)
        // by the PV b128 fragments: 0*NaN = NaN, so they must be real zeros.
        for (int t = tid; t < 384 * 8; t += 512) {
            int r = t >> 3, c = t & 7;
            vt[r * VT_STRIDE + 48 + c] = (bf16_t)0.f;
        }
        if (tid < 16) vt[384 * VT_STRIDE + tid] = (bf16_t)0.f;

        const float* xg = x + (size_t)b * (N_ * C_);
        for (int t = tid; t < (N_ * C_) / 4; t += 512) {
            float4 v = ((const float4*)xg)[t];
            int r = t / 96, c4 = t % 96;
            bf16x4 o;
            o[0] = (bf16_t)v.x; o[1] = (bf16_t)v.y;
            o[2] = (bf16_t)v.z; o[3] = (bf16_t)v.w;
            *(bf16x4*)(xs + r * XS_STRIDE + c4 * 4) = o;
        }
    }
    __syncthreads();

    // ---------------- phase 2: qkv GEMM ----------------
    // sub-A (swapped operands, q+k cols 0..767): 6 tiles/wave -> b64 epilogue
    // sub-B (normal, v cols 768..1151): 3 tiles/wave -> vT b64 epilogue
    {
        f32x4 accA[6][4], accB[3][4];
        #pragma unroll
        for (int jj = 0; jj < 6; ++jj)
            #pragma unroll
            for (int mi = 0; mi < 4; ++mi) accA[jj][mi] = z4;
        #pragma unroll
        for (int jj = 0; jj < 3; ++jj)
            #pragma unroll
            for (int mi = 0; mi < 4; ++mi) accB[jj][mi] = z4;

        for (int ks = 0; ks < 12; ++ks) {
            bf16x8 xf[4];
            #pragma unroll
            for (int mi = 0; mi < 4; ++mi)
                xf[mi] = *(const bf16x8*)(xs + (mi * 16 + l15) * XS_STRIDE + ks * 32 + q4 * 8);
            #pragma unroll
            for (int jj = 0; jj < 6; ++jj) {
                bf16x8 wf = *(const bf16x8*)(wqkvT +
                    ((size_t)((wave * 6 + jj) * 12 + ks) * 64 + lane) * 8);
                #pragma unroll
                for (int mi = 0; mi < 4; ++mi)
                    accA[jj][mi] = __builtin_amdgcn_mfma_f32_16x16x32_bf16(
                        wf, xf[mi], accA[jj][mi], 0, 0, 0);
            }
            #pragma unroll
            for (int jj = 0; jj < 3; ++jj) {
                bf16x8 wf = *(const bf16x8*)(wqkvT +
                    ((size_t)((48 + wave * 3 + jj) * 12 + ks) * 64 + lane) * 8);
                #pragma unroll
                for (int mi = 0; mi < 4; ++mi)
                    accB[jj][mi] = __builtin_amdgcn_mfma_f32_16x16x32_bf16(
                        xf[mi], wf, accB[jj][mi], 0, 0, 0);
            }
        }

        // epilogue A: C-layout (chan=ct*16+q4*4+r, tok=l15) -> q/k [tok][chan]
        #pragma unroll
        for (int jj = 0; jj < 6; ++jj) {
            const int ct = wave * 6 + jj;
            const int c0 = ct * 16 + q4 * 4;
            float4 bv = *(const float4*)(qkv_b + c0);
            bf16_t* dst = (ct < 24) ? qa : ka;
            const int cc = c0 - (ct < 24 ? 0 : C_);
            #pragma unroll
            for (int mi = 0; mi < 4; ++mi) {
                const int m = mi * 16 + l15;
                if (m < N_) {
                    bf16x4 o;
                    o[0] = (bf16_t)(accA[jj][mi][0] + bv.x);
                    o[1] = (bf16_t)(accA[jj][mi][1] + bv.y);
                    o[2] = (bf16_t)(accA[jj][mi][2] + bv.z);
                    o[3] = (bf16_t)(accA[jj][mi][3] + bv.w);
                    *(bf16x4*)(dst + m * XS_STRIDE + cc) = o;
                }
            }
        }
        // epilogue B: C-layout (tok=q4*4+r+mi*16, chan=ct*16+l15) -> vT [dim][tok]
        #pragma unroll
        for (int jj = 0; jj < 3; ++jj) {
            const int ct = 48 + wave * 3 + jj;
            const int c  = ct * 16 + l15;
            const int d  = c - 2 * C_;   // v dim 0..383
            const float bb = qkv_b[c];
            #pragma unroll
            for (int mi = 0; mi < 4; ++mi) {
                const int t0 = mi * 16 + q4 * 4;
                if (t0 + 3 < N_) {
                    bf16x4 o;
                    #pragma unroll
                    for (int r = 0; r < 4; ++r) o[r] = (bf16_t)(accB[jj][mi][r] + bb);
                    *(bf16x4*)(vt + d * VT_STRIDE + t0) = o;
                } else {
                    #pragma unroll
                    for (int r = 0; r < 4; ++r)
                        if (t0 + r < N_)
                            vt[d * VT_STRIDE + t0 + r] = (bf16_t)(accB[jj][mi][r] + bb);
                }
            }
        }
    }
    __syncthreads();

    // ---------------- phase 3: attention, 24 query-halves over 8 waves ------
    // half = wave*3+i; h = half>>1; mh = half&1 (query rows mh*32..mh*32+31)
    f32x4 oak[3][2][2];
    {
        bf16_t* pb = (bf16_t*)(smem + wave * 4608);   // 32 x 72 bf16 (xs dead)
        const bf16_t* tb = btbl + (size_t)((b & (NW_ - 1)) * H_) * (N_ * 64);
        const float SC = 0.17677669529663687f * 1.4426950408889634f;

        #pragma unroll
        for (int i = 0; i < 3; ++i) {
            const int half = wave * 3 + i;
            const int h = half >> 1, mh = half & 1;

            bf16x8 qf[2], kf[4];
            #pragma unroll
            for (int ml = 0; ml < 2; ++ml)
                qf[ml] = *(const bf16x8*)(qa + (mh * 32 + ml * 16 + l15) * XS_STRIDE
                                             + h * D_ + q4 * 8);
            #pragma unroll
            for (int ni = 0; ni < 4; ++ni)
                kf[ni] = *(const bf16x8*)(ka + (ni * 16 + l15) * XS_STRIDE
                                             + h * D_ + q4 * 8);
            // S^T[n][m]
            f32x4 sacc[4][2];
            #pragma unroll
            for (int ni = 0; ni < 4; ++ni)
                #pragma unroll
                for (int ml = 0; ml < 2; ++ml)
                    sacc[ni][ml] = __builtin_amdgcn_mfma_f32_16x16x32_bf16(
                        kf[ni], qf[ml], z4, 0, 0, 0);

            // bias + exp2 + row sums (lane's m = mh*32+ml*16+l15)
            float den[2] = {0.f, 0.f};
            #pragma unroll
            for (int ml = 0; ml < 2; ++ml) {
                const int m = mh * 32 + ml * 16 + l15;
                const int mc = m < 48 ? m : 48;
                #pragma unroll
                for (int ni = 0; ni < 4; ++ni) {
                    bf16x4 bv = *(const bf16x4*)(tb + ((size_t)h * N_ + mc) * 64
                                                    + ni * 16 + q4 * 4);
                    #pragma unroll
                    for (int r = 0; r < 4; ++r) {
                        const int n = ni * 16 + q4 * 4 + r;
                        float s = 0.f;
                        if (n < N_)
                            s = __builtin_exp2f(sacc[ni][ml][r] * SC + (float)bv[r]);
                        sacc[ni][ml][r] = s;
                        den[ml] += s;
                    }
                }
                den[ml] += __shfl_xor(den[ml], 16);
                den[ml] += __shfl_xor(den[ml], 32);
            }

            // P[m][n] b64 writes (exact zeros for n>=49; rows m>=49 skipped)
            #pragma unroll
            for (int ml = 0; ml < 2; ++ml) {
                const float ri = __builtin_amdgcn_rcpf(den[ml]);
                const int m = mh * 32 + ml * 16 + l15;
                if (m < N_) {
                    #pragma unroll
                    for (int ni = 0; ni < 4; ++ni) {
                        bf16x4 o;
                        #pragma unroll
                        for (int r = 0; r < 4; ++r) o[r] = (bf16_t)(sacc[ni][ml][r] * ri);
                        *(bf16x4*)(pb + (ml * 16 + l15) * P_STRIDE + ni * 16 + q4 * 4) = o;
                    }
                }
            }

            // out = P @ V
            #pragma unroll
            for (int ml = 0; ml < 2; ++ml)
                #pragma unroll
                for (int dt = 0; dt < 2; ++dt) oak[i][ml][dt] = z4;
            #pragma unroll
            for (int ks2 = 0; ks2 < 2; ++ks2) {
                bf16x8 pf[2], vf[2];
                #pragma unroll
                for (int ml = 0; ml < 2; ++ml)
                    pf[ml] = *(const bf16x8*)(pb + (ml * 16 + l15) * P_STRIDE
                                                 + ks2 * 32 + q4 * 8);
                #pragma unroll
                for (int dt = 0; dt < 2; ++dt)
                    vf[dt] = *(const bf16x8*)(vt + (h * D_ + dt * 16 + l15) * VT_STRIDE
                                                 + ks2 * 32 + q4 * 8);
                #pragma unroll
                for (int ml = 0; ml < 2; ++ml)
                    #pragma unroll
                    for (int dt = 0; dt < 2; ++dt)
                        oak[i][ml][dt] = __builtin_amdgcn_mfma_f32_16x16x32_bf16(
                            pf[ml], vf[dt], oak[i][ml][dt], 0, 0, 0);
            }
        }
    }
    __syncthreads();   // all q reads done before ao overwrites region 1

    // stage attn_out into region 1 (C-layout: m=q4*4+r, dcol=l15)
    {
        #pragma unroll
        for (int i = 0; i < 3; ++i) {
            const int half = wave * 3 + i;
            const int h = half >> 1, mh = half & 1;
            #pragma unroll
            for (int ml = 0; ml < 2; ++ml)
                #pragma unroll
                for (int dt = 0; dt < 2; ++dt) {
                    const int c = h * D_ + dt * 16 + l15;
                    #pragma unroll
                    for (int r = 0; r < 4; ++r) {
                        const int m = mh * 32 + ml * 16 + q4 * 4 + r;
                        if (m < N_) qa[m * XS_STRIDE + c] = (bf16_t)oak[i][ml][dt][r];
                    }
                }
        }
    }
    __syncthreads();

    // ---------------- phase 4: out = ao @ Wproj + b ----------------
    {
        f32x4 pacc[3][4];
        #pragma unroll
        for (int jj = 0; jj < 3; ++jj)
            #pragma unroll
            for (int mi = 0; mi < 4; ++mi) pacc[jj][mi] = z4;

        for (int ks = 0; ks < 12; ++ks) {
            bf16x8 af[4];
            #pragma unroll
            for (int mi = 0; mi < 4; ++mi)
                af[mi] = *(const bf16x8*)(qa + (mi * 16 + l15) * XS_STRIDE + ks * 32 + q4 * 8);
            #pragma unroll
            for (int jj = 0; jj < 3; ++jj) {
                bf16x8 wf = *(const bf16x8*)(wprojT +
                    ((size_t)((wave * 3 + jj) * 12 + ks) * 64 + lane) * 8);
                #pragma unroll
                for (int mi = 0; mi < 4; ++mi)
                    pacc[jj][mi] = __builtin_amdgcn_mfma_f32_16x16x32_bf16(
                        af[mi], wf, pacc[jj][mi], 0, 0, 0);
            }
        }
        float* og = out + (size_t)b * (N_ * C_);
        #pragma unroll
        for (int jj = 0; jj < 3; ++jj) {
            const int n = (wave * 3 + jj) * 16 + l15;
            const float bias = proj_b[n];
            #pragma unroll
            for (int mi = 0; mi < 4; ++mi) {
                #pragma unroll
                for (int r = 0; r < 4; ++r) {
                    const int m = mi * 16 + q4 * 4 + r;
                    if (m < N_) og[m * C_ + n] = pacc[jj][mi][r] + bias;
                }
            }
        }
    }
}

// ---------------------------------------------------------------------------
extern "C" void kernel_launch(void* const* d_in, const int* in_sizes, int n_in,
                              void* d_out, int out_size, void* d_ws, size_t ws_size,
                              hipStream_t stream)
{
    const float* x      = (const float*)d_in[0];
    const float* mask   = (const float*)d_in[1];
    const float* qkv_w  = (const float*)d_in[2];
    const float* qkv_b  = (const float*)d_in[3];
    const float* proj_w = (const float*)d_in[4];
    const float* proj_b = (const float*)d_in[5];
    const float* rpb    = (const float*)d_in[6];
    float* out = (float*)d_out;

    bf16_t* wqkvT  = (bf16_t*)d_ws;
    bf16_t* wprojT = wqkvT + WQKV_ELEMS;
    bf16_t* btbl   = wprojT + WPROJ_ELEMS;   // 64*12*49*64 bf16 = 4.8 MB

    prep_w<<<288, 256, 0, stream>>>(qkv_w, proj_w, wqkvT, wprojT);
    prep_bias<<<NW_ * H_, 256, 0, stream>>>(mask, rpb, btbl);
    fused_window_attn<<<2048, 512, 0, stream>>>(x, qkv_b, proj_b,
                                                wqkvT, wprojT, btbl, out);
}